// Round 4
// baseline (1049.330 us; speedup 1.0000x reference)
//
#include <hip/hip_runtime.h>

#define DEVI __device__ __forceinline__

typedef __attribute__((ext_vector_type(8))) short s16x8;
typedef __attribute__((ext_vector_type(4))) short s16x4;
typedef __attribute__((ext_vector_type(4))) float f32x4;

constexpr int B_ = 2, H_ = 16, T_ = 2048, D_ = 64;
constexpr int QT = 16;              // q rows per block
constexpr int THREADS = 512;        // 8 waves
constexpr int SROW = T_ + 8;        // padded fp16 row (bank-conflict break)
constexpr float SCALE = 0.125f;     // 1/sqrt(64)
constexpr float NEG_INF = -1e9f;

DEVI unsigned short f2bf(float x) {
    unsigned int u = __builtin_bit_cast(unsigned int, x);
    u = u + 0x7fffu + ((u >> 16) & 1u);   // RNE
    return (unsigned short)(u >> 16);
}
DEVI float bf2f(unsigned short h) {
    unsigned int u = ((unsigned int)h) << 16;
    return __builtin_bit_cast(float, u);
}
DEVI unsigned short f2h(float x) {
    _Float16 h = (_Float16)x;
    return __builtin_bit_cast(unsigned short, h);
}
DEVI float h2f(unsigned short u) {
    _Float16 h = __builtin_bit_cast(_Float16, u);
    return (float)h;
}

// split two f32x4 (8 consecutive values) into bf16 hi + lo fragments
DEVI void split8(const f32x4 a, const f32x4 b, s16x8& hi, s16x8& lo) {
#pragma unroll
    for (int e = 0; e < 4; ++e) {
        unsigned short u = f2bf(a[e]);
        hi[e] = (short)u; lo[e] = (short)f2bf(a[e] - bf2f(u));
        unsigned short v = f2bf(b[e]);
        hi[4 + e] = (short)v; lo[4 + e] = (short)f2bf(b[e] - bf2f(v));
    }
}

__global__ __launch_bounds__(THREADS, 4)
void attn_kernel(const float* __restrict__ qp, const float* __restrict__ kp,
                 const float* __restrict__ vp, const int* __restrict__ maskp,
                 const float* __restrict__ biasp, float* __restrict__ outp,
                 float* __restrict__ attnp)
{
    __shared__ alignas(16) unsigned short S[QT][SROW];   // 65792 B : fp16 scores -> bf16 p
    __shared__ alignas(16) float ORED[8][QT][16];        // 8192 B  : cross-wave O reduce
    __shared__ float ML[QT][2];                          // row max, 1/sum

    const int tid  = threadIdx.x;
    const int lane = tid & 63;
    const int w    = tid >> 6;      // wave 0..7
    const int r16  = lane & 15;
    const int g4   = lane >> 4;     // 0..3

    const int bid = blockIdx.x;
    const int qt  = bid & 127;
    const int b   = (bid >> 7) & 1;
    const int h   = bid >> 8;       // h slowest: resident blocks share bias[h] in L3
    const int q0  = qt * QT;

    const size_t bh = (size_t)(b * H_ + h);
    const float* qb    = qp + (bh * T_ + q0) * D_;
    const float* kb    = kp + bh * T_ * D_;
    const float* vb    = vp + bh * T_ * D_;
    const float* biasb = biasp + (size_t)h * T_ * T_ + (size_t)q0 * T_;
    const int*   maskb = maskp + b * T_;
    float* outb  = outp  + (bh * T_ + q0) * D_;
    float* attnb = attnp + (bh * T_ + q0) * T_;

    // ---- Q fragments (hi/lo bf16 split); identical in every wave ----
    s16x8 qh0, qh1, ql0, ql1;
    {
        const float* qrow = qb + (size_t)r16 * D_ + g4 * 8;
        const f32x4 a0 = *(const f32x4*)(qrow);
        const f32x4 a1 = *(const f32x4*)(qrow + 4);
        const f32x4 b0 = *(const f32x4*)(qrow + 32);
        const f32x4 b1 = *(const f32x4*)(qrow + 36);
        split8(a0, a1, qh0, ql0);
        split8(b0, b1, qh1, ql1);
    }

    // ---- Pass A: S = Q K^T * scale + bias, masked; fp16 to LDS ----
    // wave w owns k-tiles {w, w+8, ...}; no barriers needed until the end.
    for (int t = w; t < T_ / 16; t += 8) {
        const int c0 = t * 16;
        const float* krow = kb + (size_t)(c0 + r16) * D_ + g4 * 8;
        const f32x4 k0 = *(const f32x4*)(krow);
        const f32x4 k1 = *(const f32x4*)(krow + 4);
        const f32x4 k2 = *(const f32x4*)(krow + 32);
        const f32x4 k3 = *(const f32x4*)(krow + 36);
        s16x8 bh0, bl0, bh1, bl1;
        split8(k0, k1, bh0, bl0);
        split8(k2, k3, bh1, bl1);

        f32x4 acc = {0.f, 0.f, 0.f, 0.f};
        acc = __builtin_amdgcn_mfma_f32_16x16x32_bf16(qh0, bh0, acc, 0, 0, 0);
        acc = __builtin_amdgcn_mfma_f32_16x16x32_bf16(qh1, bh1, acc, 0, 0, 0);
        acc = __builtin_amdgcn_mfma_f32_16x16x32_bf16(ql0, bh0, acc, 0, 0, 0);
        acc = __builtin_amdgcn_mfma_f32_16x16x32_bf16(ql1, bh1, acc, 0, 0, 0);
        acc = __builtin_amdgcn_mfma_f32_16x16x32_bf16(qh0, bl0, acc, 0, 0, 0);
        acc = __builtin_amdgcn_mfma_f32_16x16x32_bf16(qh1, bl1, acc, 0, 0, 0);

        const int col = c0 + r16;
        const int mv  = maskb[col];
        const float* bp = biasb + (size_t)(g4 * 4) * T_ + col;
#pragma unroll
        for (int j = 0; j < 4; ++j) {
            float s = acc[j] * SCALE + bp[(size_t)j * T_];
            if (mv == 0) s = NEG_INF;
            S[g4 * 4 + j][col] = f2h(s);   // -1e9 -> -inf in fp16: exp()==0, as intended
        }
    }
    __syncthreads();

    // ---- Pass A.5: per-row max and sum(exp) ----
    {
        const int row = tid >> 5;   // 0..15
        const int c   = tid & 31;   // 32 threads per row (one 32-lane group)
        float m = -3.0e38f;
#pragma unroll
        for (int i = 0; i < 16; ++i) {
            s16x4 sv = *(const s16x4*)&S[row][c * 4 + i * 128];
            m = fmaxf(m, fmaxf(fmaxf(h2f((unsigned short)sv[0]), h2f((unsigned short)sv[1])),
                               fmaxf(h2f((unsigned short)sv[2]), h2f((unsigned short)sv[3]))));
        }
#pragma unroll
        for (int off = 16; off >= 1; off >>= 1) m = fmaxf(m, __shfl_xor(m, off));
        if (m < -1.0e30f) m = 0.f;   // all-masked guard (unreachable in practice)
        float l = 0.f;
#pragma unroll
        for (int i = 0; i < 16; ++i) {
            s16x4 sv = *(const s16x4*)&S[row][c * 4 + i * 128];
            l += __expf(h2f((unsigned short)sv[0]) - m) + __expf(h2f((unsigned short)sv[1]) - m)
               + __expf(h2f((unsigned short)sv[2]) - m) + __expf(h2f((unsigned short)sv[3]) - m);
        }
#pragma unroll
        for (int off = 16; off >= 1; off >>= 1) l += __shfl_xor(l, off);
        if (c == 0) { ML[row][0] = m; ML[row][1] = (l > 0.f) ? 1.f / l : 0.f; }
    }
    __syncthreads();

    // ---- Pass B1: attn (fp32, coalesced, nontemporal) + pack p (bf16) back into S ----
    {
        const int row = tid >> 5;
        const int c   = tid & 31;
        const float m    = ML[row][0];
        const float invl = ML[row][1];
        float* arow = attnb + (size_t)row * T_;
#pragma unroll 4
        for (int i = 0; i < 16; ++i) {
            const int col = c * 4 + i * 128;
            s16x4 sv = *(const s16x4*)&S[row][col];
            float p0 = __expf(h2f((unsigned short)sv[0]) - m) * invl;
            float p1 = __expf(h2f((unsigned short)sv[1]) - m) * invl;
            float p2 = __expf(h2f((unsigned short)sv[2]) - m) * invl;
            float p3 = __expf(h2f((unsigned short)sv[3]) - m) * invl;
            f32x4 pv = {p0, p1, p2, p3};
            __builtin_nontemporal_store(pv, (f32x4*)(arow + col));  // write-once stream: keep L2 for bias/V
            s16x4 pb;
            pb[0] = (short)f2bf(p0); pb[1] = (short)f2bf(p1);
            pb[2] = (short)f2bf(p2); pb[3] = (short)f2bf(p3);
            *(s16x4*)&S[row][col] = pb;
        }
    }
    __syncthreads();

    // ---- Pass B2: O = P · V (wave = (d-tile, k-half)); V loaded direct from global ----
    {
        const int dt = w & 3;              // d-tile (16 cols)
        const int ks = w >> 2;             // k half (1024)
        const int d0 = dt * 16 + r16;      // this lane's d column
        f32x4 acc = {0.f, 0.f, 0.f, 0.f};
        const float* vcol = vb + d0;
#pragma unroll 2
        for (int step = 0; step < 32; ++step) {
            const int kloc = ks * 1024 + step * 32 + g4 * 8;
            s16x8 pa = *(const s16x8*)&S[r16][kloc];
            const float* vptr = vcol + (size_t)kloc * D_;
            s16x8 vf;
#pragma unroll
            for (int e = 0; e < 8; ++e) vf[e] = (short)f2bf(vptr[(size_t)e * D_]);
            acc = __builtin_amdgcn_mfma_f32_16x16x32_bf16(pa, vf, acc, 0, 0, 0);
        }
#pragma unroll
        for (int j = 0; j < 4; ++j) ORED[w][g4 * 4 + j][r16] = acc[j];
    }
    __syncthreads();

    if (tid < 256) {
        const int row = tid >> 4;
        const int dc  = (tid & 15) * 4;
        const int dt  = dc >> 4;
        f32x4 o;
#pragma unroll
        for (int e = 0; e < 4; ++e)
            o[e] = ORED[dt][row][(dc & 15) + e] + ORED[dt + 4][row][(dc & 15) + e];
        *(f32x4*)(outb + (size_t)row * D_ + dc) = o;
    }
}

extern "C" void kernel_launch(void* const* d_in, const int* in_sizes, int n_in,
                              void* d_out, int out_size, void* d_ws, size_t ws_size,
                              hipStream_t stream) {
    const float* q    = (const float*)d_in[0];
    const float* k    = (const float*)d_in[1];
    const float* v    = (const float*)d_in[2];
    const int*   mask = (const int*)d_in[3];
    const float* bias = (const float*)d_in[4];
    float* out  = (float*)d_out;
    float* attn = out + (size_t)B_ * H_ * T_ * D_;   // tuple: (output, attn) concatenated

    dim3 grid(B_ * H_ * (T_ / QT));   // 4096 blocks; h is slowest for bias L3 reuse
    attn_kernel<<<grid, THREADS, 0, stream>>>(q, k, v, mask, bias, out, attn);
}